// Round 5
// baseline (542.820 us; speedup 1.0000x reference)
//
#include <hip/hip_runtime.h>
#include <stdint.h>

// Problem constants
#define DM   2048
#define NH   16
#define HD   128
#define BB   2
#define SS   2048
#define MM   (BB*SS)     // 4096
#define KK   2048
#define NQKV (3*DM)      // 6144

#define LOG2E  1.4426950408889634f
#define SCALE  0.08838834764831845f   // 1/sqrt(128)

using bf16x8 = __attribute__((ext_vector_type(8))) __bf16;
using f32x4  = __attribute__((ext_vector_type(4))) float;
typedef unsigned short u16;
typedef unsigned int   u32;

__device__ __forceinline__ u16 f2bf(float f) {
  u32 u = __float_as_uint(f);
  u32 r = (u + 0x7FFFu + ((u >> 16) & 1u)) >> 16;   // RNE
  return (u16)r;
}

// async global->LDS, 16B per lane. LDS dest must be wave-uniform base + lane*16.
__device__ __forceinline__ void load_lds16(const void* g, void* l) {
  __builtin_amdgcn_global_load_lds(
      (__attribute__((address_space(1))) void*)(g),
      (__attribute__((address_space(3))) void*)(l), 16, 0, 0);
}

// ---------------- cast fp32 -> bf16 (4 elems/thread) ----------------
__global__ void cast_f32_bf16(const float* __restrict__ s, u16* __restrict__ d, int n) {
  int i = (blockIdx.x * blockDim.x + threadIdx.x) * 4;
  if (i < n) {
    float4 f = *(const float4*)(s + i);
    u32 lo = (u32)f2bf(f.x) | ((u32)f2bf(f.y) << 16);
    u32 hi = (u32)f2bf(f.z) | ((u32)f2bf(f.w) << 16);
    *(uint2*)(d + i) = make_uint2(lo, hi);
  }
}

// ---------------- "RoPE" factor table ----------------
// THE REFERENCE'S _rotate_half IS THE IDENTITY (it splits the 128-dim head
// vector at HEAD_DIM=128 -> x2 empty). So q <- q*(cos+sin) elementwise.
// f[s][j] = cos(s*inv[j&63]) + sin(s*inv[j&63]), j in [0,128).
__global__ void rope_fct(float* __restrict__ f) {
  int i = blockIdx.x * blockDim.x + threadIdx.x;   // SS*128 threads
  if (i < SS * 128) {
    int s = i >> 7, j = i & 127;
    double inv = pow(10000.0, -(double)(j & 63) / 64.0);
    float ang = (float)s * (float)inv;   // fp32 product, matching reference
    float sn, cs;
    sincosf(ang, &sn, &cs);
    f[i] = cs + sn;
  }
}

// ---------------- QKV GEMM (M=4096, N=6144, K=2048) + fused q/k scaling -----
// A: x bf16 (M x K row-major). Bm: [Wq;Wk;Wv] bf16 (N x K row-major).
// Wave layout: 4 waves x (32 rows x 128 cols); block tile 128x128, BK=32.
__global__ __launch_bounds__(256, 2)
void gemm_qkv_rope(const u16* __restrict__ A, const u16* __restrict__ Bm,
                   u16* __restrict__ qo, u16* __restrict__ ko, u16* __restrict__ vo,
                   const float* __restrict__ fct) {
  __shared__ __align__(16) u16 As[128 * 32];
  __shared__ __align__(16) u16 Bs[128 * 32];
  const int tid = threadIdx.x;
  const int w = tid >> 6, lane = tid & 63, ln = lane & 15, quad = lane >> 4;
  const int m0 = blockIdx.x * 128, n0 = blockIdx.y * 128;

  const f32x4 fz = {0.f, 0.f, 0.f, 0.f};
  f32x4 acc[2][8];
#pragma unroll
  for (int mt = 0; mt < 2; mt++)
#pragma unroll
    for (int nt = 0; nt < 8; nt++) acc[mt][nt] = fz;

  for (int k0 = 0; k0 < KK; k0 += 32) {
    __syncthreads();
#pragma unroll
    for (int i = 0; i < 2; i++) {
      int tt = i * 256 + tid;
      load_lds16(A + (size_t)(m0 + (tt >> 2)) * KK + k0 + (tt & 3) * 8, (char*)As + tt * 16);
    }
#pragma unroll
    for (int i = 0; i < 2; i++) {
      int tt = i * 256 + tid;
      load_lds16(Bm + (size_t)(n0 + (tt >> 2)) * KK + k0 + (tt & 3) * 8, (char*)Bs + tt * 16);
    }
    __syncthreads();
    bf16x8 af[2];
#pragma unroll
    for (int mt = 0; mt < 2; mt++)
      af[mt] = *(const bf16x8*)&As[(w * 32 + mt * 16 + ln) * 32 + quad * 8];
#pragma unroll
    for (int nt = 0; nt < 8; nt++) {
      bf16x8 bf = *(const bf16x8*)&Bs[(nt * 16 + ln) * 32 + quad * 8];
#pragma unroll
      for (int mt = 0; mt < 2; mt++)
        acc[mt][nt] = __builtin_amdgcn_mfma_f32_16x16x32_bf16(af[mt], bf, acc[mt][nt], 0, 0, 0);
    }
  }

  // Epilogue. Block's N-range is exactly one (tensor, head): n0 % 128 == 0.
  const int tensor = n0 >> 11;          // 0:q 1:k 2:v
  const int h = (n0 & 2047) >> 7;
  if (tensor < 2) {
    u16* dst = (tensor == 0) ? qo : ko;
#pragma unroll
    for (int mt = 0; mt < 2; mt++)
#pragma unroll
      for (int r = 0; r < 4; r++) {
        int m = m0 + w * 32 + mt * 16 + quad * 4 + r;
        int b = m >> 11, s = m & 2047;
        size_t base = ((size_t)(b * NH + h) * SS + s) * HD;
        const float* fr = fct + s * 128;
#pragma unroll
        for (int nt = 0; nt < 8; nt++) {
          int j = nt * 16 + ln;
          dst[base + j] = f2bf(acc[mt][nt][r] * fr[j]);
        }
      }
  } else {
    // v: store transposed (B, NH, HD, S); pack 4 consecutive s into one 8B store
#pragma unroll
    for (int mt = 0; mt < 2; mt++)
#pragma unroll
      for (int nt = 0; nt < 8; nt++) {
        int m0r = m0 + w * 32 + mt * 16 + quad * 4;
        int b = m0r >> 11, s0 = m0r & 2047;
        int hd = nt * 16 + ln;
        u32 lo = (u32)f2bf(acc[mt][nt][0]) | ((u32)f2bf(acc[mt][nt][1]) << 16);
        u32 hi = (u32)f2bf(acc[mt][nt][2]) | ((u32)f2bf(acc[mt][nt][3]) << 16);
        *(uint2*)(vo + ((size_t)(b * NH + h) * HD + hd) * SS + s0) = make_uint2(lo, hi);
      }
  }
}

// ---------------- Flash attention ----------------
// grid (S/128, NH, B), block 256. Q-tile 128 rows, K-tile 64, online softmax.
__global__ __launch_bounds__(256, 2)
void flash_attn(const u16* __restrict__ q, const u16* __restrict__ k,
                const u16* __restrict__ v, u16* __restrict__ o) {
  __shared__ __align__(16) u16 Qs[128 * 128];   // 32KB, reused as P buffer
  __shared__ __align__(16) u16 Ks[64 * 128];    // 16KB
  __shared__ __align__(16) u16 Vs[128 * 64];    // 16KB (Vt: hd rows, s cols)
  const int tid = threadIdx.x;
  const int w = tid >> 6, lane = tid & 63, ln = lane & 15, quad = lane >> 4;
  const int qt = blockIdx.x, hh = blockIdx.y, b = blockIdx.z;
  const size_t bh = (size_t)b * NH + hh;
  const u16* Qg = q + bh * SS * HD + (size_t)qt * 128 * HD;
  const u16* Kg = k + bh * SS * HD;
  const u16* Vg = v + bh * HD * SS;

#pragma unroll
  for (int i = 0; i < 8; i++) {
    int tt = i * 256 + tid;
    load_lds16(Qg + (tt >> 4) * HD + (tt & 15) * 8, (char*)Qs + tt * 16);
  }
  __syncthreads();
  bf16x8 qf[2][4];
#pragma unroll
  for (int mt = 0; mt < 2; mt++)
#pragma unroll
    for (int kc = 0; kc < 4; kc++)
      qf[mt][kc] = *(const bf16x8*)&Qs[(w * 32 + mt * 16 + ln) * 128 + kc * 32 + quad * 8];
  __syncthreads();   // all waves done reading Q before P buffer reuse

  u16* Ps = Qs;      // wave-private region [w*32, w*32+32) x 64
  const f32x4 fz = {0.f, 0.f, 0.f, 0.f};
  float m_s[2][4], l_s[2][4];
  f32x4 accO[2][8];
#pragma unroll
  for (int mt = 0; mt < 2; mt++) {
#pragma unroll
    for (int r = 0; r < 4; r++) { m_s[mt][r] = -1e30f; l_s[mt][r] = 0.f; }
#pragma unroll
    for (int nt = 0; nt < 8; nt++) accO[mt][nt] = fz;
  }

  const int qrb = qt * 128 + w * 32;
  const int nkt = 2 * qt + 2;
  for (int kt = 0; kt < nkt; kt++) {
    const int k0 = kt * 64;
    __syncthreads();   // protect Ks/Vs from previous iteration's readers
#pragma unroll
    for (int i = 0; i < 4; i++) {
      int tt = i * 256 + tid;
      load_lds16(Kg + (size_t)(k0 + (tt >> 4)) * HD + (tt & 15) * 8, (char*)Ks + tt * 16);
    }
#pragma unroll
    for (int i = 0; i < 4; i++) {
      int tt = i * 256 + tid;
      load_lds16(Vg + (size_t)(tt >> 3) * SS + k0 + (tt & 7) * 8, (char*)Vs + tt * 16);
    }
    __syncthreads();

    // S = Q K^T  (32 q-rows x 64 k-cols per wave)
    f32x4 sc[2][4];
#pragma unroll
    for (int mt = 0; mt < 2; mt++)
#pragma unroll
      for (int nt = 0; nt < 4; nt++) sc[mt][nt] = fz;
#pragma unroll
    for (int kc = 0; kc < 4; kc++)
#pragma unroll
      for (int nt = 0; nt < 4; nt++) {
        bf16x8 bf = *(const bf16x8*)&Ks[(nt * 16 + ln) * 128 + kc * 32 + quad * 8];
#pragma unroll
        for (int mt = 0; mt < 2; mt++)
          sc[mt][nt] = __builtin_amdgcn_mfma_f32_16x16x32_bf16(qf[mt][kc], bf, sc[mt][nt], 0, 0, 0);
      }

    const bool partial = (kt >= 2 * qt);
#pragma unroll
    for (int mt = 0; mt < 2; mt++)
#pragma unroll
      for (int nt = 0; nt < 4; nt++)
#pragma unroll
        for (int r = 0; r < 4; r++) {
          float val = sc[mt][nt][r] * SCALE;
          if (partial && (k0 + nt * 16 + ln > qrb + mt * 16 + quad * 4 + r)) val = -1e9f;
          sc[mt][nt][r] = val;
        }

    // online softmax per row (rows live in 16-lane col-groups; butterfly xor 1..8)
#pragma unroll
    for (int mt = 0; mt < 2; mt++)
#pragma unroll
      for (int r = 0; r < 4; r++) {
        float mx = fmaxf(fmaxf(sc[mt][0][r], sc[mt][1][r]), fmaxf(sc[mt][2][r], sc[mt][3][r]));
#pragma unroll
        for (int off = 1; off < 16; off <<= 1) mx = fmaxf(mx, __shfl_xor(mx, off));
        float mnew = fmaxf(m_s[mt][r], mx);
        float alpha = exp2f((m_s[mt][r] - mnew) * LOG2E);
        float rs = 0.f;
#pragma unroll
        for (int nt = 0; nt < 4; nt++) {
          float p = exp2f((sc[mt][nt][r] - mnew) * LOG2E);
          sc[mt][nt][r] = p;
          rs += p;
        }
#pragma unroll
        for (int off = 1; off < 16; off <<= 1) rs += __shfl_xor(rs, off);
        l_s[mt][r] = l_s[mt][r] * alpha + rs;
        m_s[mt][r] = mnew;
#pragma unroll
        for (int nt = 0; nt < 8; nt++) accO[mt][nt][r] *= alpha;
      }

    // P: C-layout -> LDS -> A-layout (wave-private region, same-wave DS ordering)
#pragma unroll
    for (int mt = 0; mt < 2; mt++)
#pragma unroll
      for (int nt = 0; nt < 4; nt++)
#pragma unroll
        for (int r = 0; r < 4; r++)
          Ps[(w * 32 + mt * 16 + quad * 4 + r) * 64 + nt * 16 + ln] = f2bf(sc[mt][nt][r]);

    // FENCE: u16 stores vs bf16x8 loads are different TBAA types; pin order
    // and drain DS writes before the vector reads.
    __asm__ __volatile__("s_waitcnt lgkmcnt(0)" ::: "memory");

    bf16x8 pf[2][2];
#pragma unroll
    for (int mt = 0; mt < 2; mt++)
#pragma unroll
      for (int kc = 0; kc < 2; kc++)
        pf[mt][kc] = *(const bf16x8*)&Ps[(w * 32 + mt * 16 + ln) * 64 + kc * 32 + quad * 8];

    // O += P V
#pragma unroll
    for (int kc = 0; kc < 2; kc++)
#pragma unroll
      for (int nt = 0; nt < 8; nt++) {
        bf16x8 vf = *(const bf16x8*)&Vs[(nt * 16 + ln) * 64 + kc * 32 + quad * 8];
#pragma unroll
        for (int mt = 0; mt < 2; mt++)
          accO[mt][nt] = __builtin_amdgcn_mfma_f32_16x16x32_bf16(pf[mt][kc], vf, accO[mt][nt], 0, 0, 0);
      }
  }

  // normalize + store (B, S, DM) bf16
#pragma unroll
  for (int mt = 0; mt < 2; mt++)
#pragma unroll
    for (int r = 0; r < 4; r++) {
      float ilv = 1.f / l_s[mt][r];
      int srow = qt * 128 + w * 32 + mt * 16 + quad * 4 + r;
      size_t base = ((size_t)b * SS + srow) * DM + hh * HD;
#pragma unroll
      for (int nt = 0; nt < 8; nt++)
        o[base + nt * 16 + ln] = f2bf(accO[mt][nt][r] * ilv);
    }
}

// ---------------- Output GEMM (M=4096, N=2048, K=2048), fp32 epilogue --------
__global__ __launch_bounds__(256, 2)
void gemm_out(const u16* __restrict__ A, const u16* __restrict__ Bm,
              float* __restrict__ C) {
  __shared__ __align__(16) u16 As[128 * 32];
  __shared__ __align__(16) u16 Bs[128 * 32];
  const int tid = threadIdx.x;
  const int w = tid >> 6, lane = tid & 63, ln = lane & 15, quad = lane >> 4;
  const int m0 = blockIdx.x * 128, n0 = blockIdx.y * 128;

  const f32x4 fz = {0.f, 0.f, 0.f, 0.f};
  f32x4 acc[2][8];
#pragma unroll
  for (int mt = 0; mt < 2; mt++)
#pragma unroll
    for (int nt = 0; nt < 8; nt++) acc[mt][nt] = fz;

  for (int k0 = 0; k0 < KK; k0 += 32) {
    __syncthreads();
#pragma unroll
    for (int i = 0; i < 2; i++) {
      int tt = i * 256 + tid;
      load_lds16(A + (size_t)(m0 + (tt >> 2)) * KK + k0 + (tt & 3) * 8, (char*)As + tt * 16);
    }
#pragma unroll
    for (int i = 0; i < 2; i++) {
      int tt = i * 256 + tid;
      load_lds16(Bm + (size_t)(n0 + (tt >> 2)) * KK + k0 + (tt & 3) * 8, (char*)Bs + tt * 16);
    }
    __syncthreads();
    bf16x8 af[2];
#pragma unroll
    for (int mt = 0; mt < 2; mt++)
      af[mt] = *(const bf16x8*)&As[(w * 32 + mt * 16 + ln) * 32 + quad * 8];
#pragma unroll
    for (int nt = 0; nt < 8; nt++) {
      bf16x8 bf = *(const bf16x8*)&Bs[(nt * 16 + ln) * 32 + quad * 8];
#pragma unroll
      for (int mt = 0; mt < 2; mt++)
        acc[mt][nt] = __builtin_amdgcn_mfma_f32_16x16x32_bf16(af[mt], bf, acc[mt][nt], 0, 0, 0);
    }
  }

#pragma unroll
  for (int mt = 0; mt < 2; mt++)
#pragma unroll
    for (int r = 0; r < 4; r++) {
      int m = m0 + w * 32 + mt * 16 + quad * 4 + r;
#pragma unroll
      for (int nt = 0; nt < 8; nt++)
        C[(size_t)m * DM + n0 + nt * 16 + ln] = acc[mt][nt][r];
    }
}

// ---------------- launch ----------------
extern "C" void kernel_launch(void* const* d_in, const int* in_sizes, int n_in,
                              void* d_out, int out_size, void* d_ws, size_t ws_size,
                              hipStream_t stream) {
  (void)in_sizes; (void)n_in; (void)out_size; (void)ws_size;
  const float* x  = (const float*)d_in[0];
  // d_in[1] = attention_mask (exact causal tril) — implemented analytically
  const float* Wq = (const float*)d_in[2];
  const float* Wk = (const float*)d_in[3];
  const float* Wv = (const float*)d_in[4];
  const float* Wd = (const float*)d_in[5];

  // Compact workspace (96 MiB = 100,663,296 B):
  //   [0, 16M)    xb, later reused as aob
  //   [16M, 40M)  wqkv (3 x DM x KK bf16)
  //   [40M+2M=41943040, +8M) region R: fct (1 MB) during QKV, then wdb
  //   [48M, 64M)  qb   [64M, 80M) kb   [80M, 96M) vtb
  char* ws = (char*)d_ws;
  u16* xb   = (u16*)(ws);                      // 16,777,216 B
  u16* aob  = xb;                              // reuse after QKV GEMM
  u16* wqkv = (u16*)(ws + 16777216ull);        // 25,165,824 B
  float* fct = (float*)(ws + 41943040ull);     //  1,048,576 B (dead after QKV)
  u16* wdb  = (u16*)(ws + 41943040ull);        //  8,388,608 B (after fct dead)
  u16* qb   = (u16*)(ws + 50331648ull);        // 16,777,216 B
  u16* kb   = (u16*)(ws + 67108864ull);        // 16,777,216 B
  u16* vtb  = (u16*)(ws + 83886080ull);        // 16,777,216 B

  cast_f32_bf16<<<8192, 256, 0, stream>>>(x,  xb, MM * KK);
  cast_f32_bf16<<<4096, 256, 0, stream>>>(Wq, wqkv,                   DM * KK);
  cast_f32_bf16<<<4096, 256, 0, stream>>>(Wk, wqkv + (size_t)DM*KK,   DM * KK);
  cast_f32_bf16<<<4096, 256, 0, stream>>>(Wv, wqkv + (size_t)2*DM*KK, DM * KK);
  rope_fct<<<1024, 256, 0, stream>>>(fct);

  gemm_qkv_rope<<<dim3(MM / 128, NQKV / 128), 256, 0, stream>>>(xb, wqkv, qb, kb, vtb, fct);

  cast_f32_bf16<<<4096, 256, 0, stream>>>(Wd, wdb, DM * KK);   // overwrites fct (dead)

  flash_attn<<<dim3(SS / 128, NH, BB), 256, 0, stream>>>(qb, kb, vtb, aob);
  gemm_out<<<dim3(MM / 128, DM / 128), 256, 0, stream>>>(aob, wdb, (float*)d_out);
}

// Round 6
// 495.490 us; speedup vs baseline: 1.0955x; 1.0955x over previous
//
#include <hip/hip_runtime.h>
#include <stdint.h>

// Problem constants
#define DM   2048
#define NH   16
#define HD   128
#define BB   2
#define SS   2048
#define MM   (BB*SS)     // 4096
#define KK   2048
#define NQKV (3*DM)      // 6144

#define LOG2E  1.4426950408889634f
#define SCALE  0.08838834764831845f   // 1/sqrt(128)

using bf16x8 = __attribute__((ext_vector_type(8))) __bf16;
using f32x4  = __attribute__((ext_vector_type(4))) float;
typedef unsigned short u16;
typedef unsigned int   u32;

__device__ __forceinline__ u16 f2bf(float f) {
  u32 u = __float_as_uint(f);
  u32 r = (u + 0x7FFFu + ((u >> 16) & 1u)) >> 16;   // RNE
  return (u16)r;
}

// async global->LDS, 16B per lane. LDS dest must be lane-contiguous (base+tid*16).
__device__ __forceinline__ void load_lds16(const void* g, void* l) {
  __builtin_amdgcn_global_load_lds(
      (__attribute__((address_space(1))) void*)(g),
      (__attribute__((address_space(3))) void*)(l), 16, 0, 0);
}

// ---------------- cast fp32 -> bf16 (4 elems/thread) ----------------
__global__ void cast_f32_bf16(const float* __restrict__ s, u16* __restrict__ d, int n) {
  int i = (blockIdx.x * blockDim.x + threadIdx.x) * 4;
  if (i < n) {
    float4 f = *(const float4*)(s + i);
    u32 lo = (u32)f2bf(f.x) | ((u32)f2bf(f.y) << 16);
    u32 hi = (u32)f2bf(f.z) | ((u32)f2bf(f.w) << 16);
    *(uint2*)(d + i) = make_uint2(lo, hi);
  }
}

// ---------------- "RoPE" factor table ----------------
// Reference's _rotate_half is the identity (splits 128-dim head at 128).
// q <- q*(cos+sin) elementwise. f[s][j] = cos(s*inv[j&63]) + sin(s*inv[j&63]).
__global__ void rope_fct(float* __restrict__ f) {
  int i = blockIdx.x * blockDim.x + threadIdx.x;   // SS*128 threads
  if (i < SS * 128) {
    int s = i >> 7, j = i & 127;
    double inv = pow(10000.0, -(double)(j & 63) / 64.0);
    float ang = (float)s * (float)inv;
    float sn, cs;
    sincosf(ang, &sn, &cs);
    f[i] = cs + sn;
  }
}

// ---------------- QKV GEMM (M=4096, N=6144, K=2048) + fused q/k scaling -----
// A: x bf16 (M x K row-major). Bm: [Wq;Wk;Wv] bf16 (N x K row-major).
__global__ __launch_bounds__(256, 2)
void gemm_qkv_rope(const u16* __restrict__ A, const u16* __restrict__ Bm,
                   u16* __restrict__ qo, u16* __restrict__ ko, u16* __restrict__ vo,
                   const float* __restrict__ fct) {
  __shared__ __align__(16) u16 S[2][128 * 32];   // As=S[0], Bs=S[1]; 16KB total
  u16* As = S[0];
  u16* Bs = S[1];
  const int tid = threadIdx.x;
  const int w = tid >> 6, lane = tid & 63, ln = lane & 15, quad = lane >> 4;
  const int m0 = blockIdx.x * 128, n0 = blockIdx.y * 128;

  const f32x4 fz = {0.f, 0.f, 0.f, 0.f};
  f32x4 acc[2][8];
#pragma unroll
  for (int mt = 0; mt < 2; mt++)
#pragma unroll
    for (int nt = 0; nt < 8; nt++) acc[mt][nt] = fz;

  for (int k0 = 0; k0 < KK; k0 += 32) {
    __syncthreads();
#pragma unroll
    for (int i = 0; i < 2; i++) {
      int tt = i * 256 + tid;
      load_lds16(A + (size_t)(m0 + (tt >> 2)) * KK + k0 + (tt & 3) * 8, (char*)As + tt * 16);
    }
#pragma unroll
    for (int i = 0; i < 2; i++) {
      int tt = i * 256 + tid;
      load_lds16(Bm + (size_t)(n0 + (tt >> 2)) * KK + k0 + (tt & 3) * 8, (char*)Bs + tt * 16);
    }
    __syncthreads();
    bf16x8 af[2];
#pragma unroll
    for (int mt = 0; mt < 2; mt++)
      af[mt] = *(const bf16x8*)&As[(w * 32 + mt * 16 + ln) * 32 + quad * 8];
#pragma unroll
    for (int nt = 0; nt < 8; nt++) {
      bf16x8 bf = *(const bf16x8*)&Bs[(nt * 16 + ln) * 32 + quad * 8];
#pragma unroll
      for (int mt = 0; mt < 2; mt++)
        acc[mt][nt] = __builtin_amdgcn_mfma_f32_16x16x32_bf16(af[mt], bf, acc[mt][nt], 0, 0, 0);
    }
  }

  // Epilogue. Block's N-range is exactly one (tensor, head).
  const int tensor = n0 >> 11;          // 0:q 1:k 2:v
  const int h = (n0 & 2047) >> 7;
  if (tensor < 2) {
    u16* dst = (tensor == 0) ? qo : ko;
#pragma unroll
    for (int mt = 0; mt < 2; mt++)
#pragma unroll
      for (int r = 0; r < 4; r++) {
        int m = m0 + w * 32 + mt * 16 + quad * 4 + r;
        int b = m >> 11, s = m & 2047;
        size_t base = ((size_t)(b * NH + h) * SS + s) * HD;
        const float* fr = fct + s * 128;
#pragma unroll
        for (int nt = 0; nt < 8; nt++) {
          int j = nt * 16 + ln;
          dst[base + j] = f2bf(acc[mt][nt][r] * fr[j]);
        }
      }
  } else {
    // V: transpose via LDS (reuse staging buffers), coalesced 16B stores to (B,NH,HD,S)
    u16* Tr = (u16*)S;                  // 16KB: 128 hd x 64 compressed-s, swizzled
    const int b = m0 >> 11, s0 = m0 & 2047;
#pragma unroll
    for (int mt = 0; mt < 2; mt++) {
      __syncthreads();                  // Tr region free of previous readers
#pragma unroll
      for (int nt = 0; nt < 8; nt++) {
        int hd = nt * 16 + ln;
#pragma unroll
        for (int r = 0; r < 4; r++) {
          int c = w * 16 + quad * 4 + r;   // compressed s-index 0..63
          Tr[hd * 64 + (((c >> 3) ^ (hd & 7)) * 8) + (c & 7)] = f2bf(acc[mt][nt][r]);
        }
      }
      __syncthreads();
#pragma unroll
      for (int it = 0; it < 4; it++) {
        int idx = it * 256 + tid;
        int hd = idx >> 3, c8 = idx & 7;
        uint4 val = *(const uint4*)&Tr[hd * 64 + ((c8 ^ (hd & 7)) * 8)];
        int c0 = c8 * 8;
        int srel = ((c0 >> 4) * 32) + mt * 16 + (c0 & 15);
        *(uint4*)(vo + ((size_t)(b * NH + h) * HD + hd) * SS + s0 + srel) = val;
      }
    }
  }
}

// ---------------- Flash attention v3 ----------------
// grid (8, NH, B): block bx handles q-tiles {bx, 15-bx} (128 rows each) ->
// uniform 34 k-tile units/block, 1 block/CU. Double-buffered K/V staging,
// XOR-swizzled LDS (chunk' = chunk ^ (row&7)) for conflict-free ds_read_b128.
__global__ __launch_bounds__(256, 1)
void flash_attn(const u16* __restrict__ q, const u16* __restrict__ k,
                const u16* __restrict__ v, u16* __restrict__ o) {
  __shared__ __align__(16) u16 QPs[128 * 128];    // 32KB: Q staging; first 16KB = P
  __shared__ __align__(16) u16 Ks[2][64 * 128];   // 2 x 16KB
  __shared__ __align__(16) u16 Vs[2][128 * 64];   // 2 x 16KB (Vt: hd rows, k cols)
  const int tid = threadIdx.x;
  const int w = tid >> 6, lane = tid & 63, ln = lane & 15, quad = lane >> 4;
  const int hh = blockIdx.y, b = blockIdx.z;
  const size_t bh = (size_t)b * NH + hh;
  const u16* Kg = k + bh * SS * HD;
  const u16* Vg = v + bh * HD * SS;

  for (int half = 0; half < 2; half++) {
    const int T = half ? (15 - (int)blockIdx.x) : (int)blockIdx.x;
    const u16* Qg = q + bh * SS * HD + (size_t)T * 128 * HD;

    __syncthreads();   // QPs/Ks/Vs free of previous tile's readers

    // stage Q (32KB, swizzled): slot -> (row r, phys chunk cp), fetch logical cp^(r&7)
#pragma unroll
    for (int i = 0; i < 8; i++) {
      int slot = i * 256 + tid;
      int r = slot >> 4, c = (slot & 15) ^ (r & 7);
      load_lds16(Qg + (size_t)r * HD + c * 8, (char*)QPs + slot * 16);
    }
    __asm__ __volatile__("s_waitcnt vmcnt(0)" ::: "memory");
    __syncthreads();

    bf16x8 qf[2][4];
#pragma unroll
    for (int mt = 0; mt < 2; mt++)
#pragma unroll
      for (int kc = 0; kc < 4; kc++) {
        int rq = w * 32 + mt * 16 + ln;
        qf[mt][kc] = *(const bf16x8*)&QPs[rq * 128 + (((kc * 4 + quad) ^ (ln & 7)) * 8)];
      }

    const f32x4 fz = {0.f, 0.f, 0.f, 0.f};
    float m_s[2][4], l_s[2][4];
    f32x4 accO[2][8];
#pragma unroll
    for (int mt = 0; mt < 2; mt++) {
#pragma unroll
      for (int r = 0; r < 4; r++) { m_s[mt][r] = -1e30f; l_s[mt][r] = 0.f; }
#pragma unroll
      for (int nt = 0; nt < 8; nt++) accO[mt][nt] = fz;
    }

    const int nkt = 2 * T + 2;
    const int qrb = T * 128 + w * 32;

    // prefetch kt=0 into buffer 0
#pragma unroll
    for (int i = 0; i < 4; i++) {
      int slot = i * 256 + tid;
      int r = slot >> 4, c = (slot & 15) ^ (r & 7);
      load_lds16(Kg + (size_t)r * HD + c * 8, (char*)Ks[0] + slot * 16);
    }
#pragma unroll
    for (int i = 0; i < 4; i++) {
      int slot = i * 256 + tid;
      int r = slot >> 3, c = (slot & 7) ^ (r & 7);
      load_lds16(Vg + (size_t)r * SS + c * 8, (char*)Vs[0] + slot * 16);
    }

    for (int kt = 0; kt < nkt; kt++) {
      const int cur = kt & 1;
      const int k0 = kt * 64;
      // drain the staging issued one iteration ago (latency already hidden)
      __asm__ __volatile__("s_waitcnt vmcnt(0)" ::: "memory");
      __syncthreads();
      if (kt + 1 < nkt) {   // prefetch next k-tile into the other buffer
        const int kn = k0 + 64;
#pragma unroll
        for (int i = 0; i < 4; i++) {
          int slot = i * 256 + tid;
          int r = slot >> 4, c = (slot & 15) ^ (r & 7);
          load_lds16(Kg + (size_t)(kn + r) * HD + c * 8, (char*)Ks[cur ^ 1] + slot * 16);
        }
#pragma unroll
        for (int i = 0; i < 4; i++) {
          int slot = i * 256 + tid;
          int r = slot >> 3, c = (slot & 7) ^ (r & 7);
          load_lds16(Vg + (size_t)r * SS + kn + c * 8, (char*)Vs[cur ^ 1] + slot * 16);
        }
      }

      // S = Q K^T  (32 q-rows x 64 k-cols per wave)
      f32x4 sc[2][4];
#pragma unroll
      for (int mt = 0; mt < 2; mt++)
#pragma unroll
        for (int nt = 0; nt < 4; nt++) sc[mt][nt] = fz;
#pragma unroll
      for (int kc = 0; kc < 4; kc++)
#pragma unroll
        for (int nt = 0; nt < 4; nt++) {
          bf16x8 bf = *(const bf16x8*)&Ks[cur][(nt * 16 + ln) * 128 + (((kc * 4 + quad) ^ (ln & 7)) * 8)];
#pragma unroll
          for (int mt = 0; mt < 2; mt++)
            sc[mt][nt] = __builtin_amdgcn_mfma_f32_16x16x32_bf16(qf[mt][kc], bf, sc[mt][nt], 0, 0, 0);
        }

      const bool partial = (kt >= 2 * T);
#pragma unroll
      for (int mt = 0; mt < 2; mt++)
#pragma unroll
        for (int nt = 0; nt < 4; nt++)
#pragma unroll
          for (int r = 0; r < 4; r++) {
            float val = sc[mt][nt][r] * SCALE;
            if (partial && (k0 + nt * 16 + ln > qrb + mt * 16 + quad * 4 + r)) val = -1e9f;
            sc[mt][nt][r] = val;
          }

      // online softmax per row
#pragma unroll
      for (int mt = 0; mt < 2; mt++)
#pragma unroll
        for (int r = 0; r < 4; r++) {
          float mx = fmaxf(fmaxf(sc[mt][0][r], sc[mt][1][r]), fmaxf(sc[mt][2][r], sc[mt][3][r]));
#pragma unroll
          for (int off = 1; off < 16; off <<= 1) mx = fmaxf(mx, __shfl_xor(mx, off));
          float mnew = fmaxf(m_s[mt][r], mx);
          float alpha = exp2f((m_s[mt][r] - mnew) * LOG2E);
          float rs = 0.f;
#pragma unroll
          for (int nt = 0; nt < 4; nt++) {
            float p = exp2f((sc[mt][nt][r] - mnew) * LOG2E);
            sc[mt][nt][r] = p;
            rs += p;
          }
#pragma unroll
          for (int off = 1; off < 16; off <<= 1) rs += __shfl_xor(rs, off);
          l_s[mt][r] = l_s[mt][r] * alpha + rs;
          m_s[mt][r] = mnew;
#pragma unroll
          for (int nt = 0; nt < 8; nt++) accO[mt][nt][r] *= alpha;
        }

      // P: C-layout -> LDS (swizzled, wave-private slab) -> A-layout
#pragma unroll
      for (int mt = 0; mt < 2; mt++)
#pragma unroll
        for (int nt = 0; nt < 4; nt++)
#pragma unroll
          for (int r = 0; r < 4; r++) {
            int rr = w * 32 + mt * 16 + quad * 4 + r;
            int j = nt * 16 + ln;
            QPs[rr * 64 + (((j >> 3) ^ (rr & 7)) * 8) + (j & 7)] = f2bf(sc[mt][nt][r]);
          }
      __asm__ __volatile__("s_waitcnt lgkmcnt(0)" ::: "memory");

      bf16x8 pf[2][2];
#pragma unroll
      for (int mt = 0; mt < 2; mt++)
#pragma unroll
        for (int kc = 0; kc < 2; kc++) {
          int rp = w * 32 + mt * 16 + ln;
          pf[mt][kc] = *(const bf16x8*)&QPs[rp * 64 + (((kc * 4 + quad) ^ (ln & 7)) * 8)];
        }

      // O += P V
#pragma unroll
      for (int kc = 0; kc < 2; kc++)
#pragma unroll
        for (int nt = 0; nt < 8; nt++) {
          bf16x8 vf = *(const bf16x8*)&Vs[cur][(nt * 16 + ln) * 64 + (((kc * 4 + quad) ^ (ln & 7)) * 8)];
#pragma unroll
          for (int mt = 0; mt < 2; mt++)
            accO[mt][nt] = __builtin_amdgcn_mfma_f32_16x16x32_bf16(pf[mt][kc], vf, accO[mt][nt], 0, 0, 0);
        }
    }

    // normalize + store (B, S, DM) bf16
#pragma unroll
    for (int mt = 0; mt < 2; mt++)
#pragma unroll
      for (int r = 0; r < 4; r++) {
        float ilv = 1.f / l_s[mt][r];
        int srow = T * 128 + w * 32 + mt * 16 + quad * 4 + r;
        size_t base = ((size_t)b * SS + srow) * DM + hh * HD;
#pragma unroll
        for (int nt = 0; nt < 8; nt++)
          o[base + nt * 16 + ln] = f2bf(accO[mt][nt][r] * ilv);
      }
  }
}

// ---------------- Output GEMM (M=4096, N=2048, K=2048), fp32 epilogue --------
__global__ __launch_bounds__(256, 2)
void gemm_out(const u16* __restrict__ A, const u16* __restrict__ Bm,
              float* __restrict__ C) {
  __shared__ __align__(16) u16 As[128 * 32];
  __shared__ __align__(16) u16 Bs[128 * 32];
  const int tid = threadIdx.x;
  const int w = tid >> 6, lane = tid & 63, ln = lane & 15, quad = lane >> 4;
  const int m0 = blockIdx.x * 128, n0 = blockIdx.y * 128;

  const f32x4 fz = {0.f, 0.f, 0.f, 0.f};
  f32x4 acc[2][8];
#pragma unroll
  for (int mt = 0; mt < 2; mt++)
#pragma unroll
    for (int nt = 0; nt < 8; nt++) acc[mt][nt] = fz;

  for (int k0 = 0; k0 < KK; k0 += 32) {
    __syncthreads();
#pragma unroll
    for (int i = 0; i < 2; i++) {
      int tt = i * 256 + tid;
      load_lds16(A + (size_t)(m0 + (tt >> 2)) * KK + k0 + (tt & 3) * 8, (char*)As + tt * 16);
    }
#pragma unroll
    for (int i = 0; i < 2; i++) {
      int tt = i * 256 + tid;
      load_lds16(Bm + (size_t)(n0 + (tt >> 2)) * KK + k0 + (tt & 3) * 8, (char*)Bs + tt * 16);
    }
    __syncthreads();
    bf16x8 af[2];
#pragma unroll
    for (int mt = 0; mt < 2; mt++)
      af[mt] = *(const bf16x8*)&As[(w * 32 + mt * 16 + ln) * 32 + quad * 8];
#pragma unroll
    for (int nt = 0; nt < 8; nt++) {
      bf16x8 bf = *(const bf16x8*)&Bs[(nt * 16 + ln) * 32 + quad * 8];
#pragma unroll
      for (int mt = 0; mt < 2; mt++)
        acc[mt][nt] = __builtin_amdgcn_mfma_f32_16x16x32_bf16(af[mt], bf, acc[mt][nt], 0, 0, 0);
    }
  }

#pragma unroll
  for (int mt = 0; mt < 2; mt++)
#pragma unroll
    for (int r = 0; r < 4; r++) {
      int m = m0 + w * 32 + mt * 16 + quad * 4 + r;
#pragma unroll
      for (int nt = 0; nt < 8; nt++)
        C[(size_t)m * DM + n0 + nt * 16 + ln] = acc[mt][nt][r];
    }
}

// ---------------- launch ----------------
extern "C" void kernel_launch(void* const* d_in, const int* in_sizes, int n_in,
                              void* d_out, int out_size, void* d_ws, size_t ws_size,
                              hipStream_t stream) {
  (void)in_sizes; (void)n_in; (void)out_size; (void)ws_size;
  const float* x  = (const float*)d_in[0];
  // d_in[1] = attention_mask (exact causal tril) — implemented analytically
  const float* Wq = (const float*)d_in[2];
  const float* Wk = (const float*)d_in[3];
  const float* Wv = (const float*)d_in[4];
  const float* Wd = (const float*)d_in[5];

  // Workspace (96 MiB):
  //   [0,16M) xb (reused as aob)  [16M,40M) wqkv  [40M..] fct then wdb
  //   [48M,64M) qb  [64M,80M) kb  [80M,96M) vtb
  char* ws = (char*)d_ws;
  u16* xb   = (u16*)(ws);
  u16* aob  = xb;
  u16* wqkv = (u16*)(ws + 16777216ull);
  float* fct = (float*)(ws + 41943040ull);
  u16* wdb  = (u16*)(ws + 41943040ull);
  u16* qb   = (u16*)(ws + 50331648ull);
  u16* kb   = (u16*)(ws + 67108864ull);
  u16* vtb  = (u16*)(ws + 83886080ull);

  cast_f32_bf16<<<8192, 256, 0, stream>>>(x,  xb, MM * KK);
  cast_f32_bf16<<<4096, 256, 0, stream>>>(Wq, wqkv,                   DM * KK);
  cast_f32_bf16<<<4096, 256, 0, stream>>>(Wk, wqkv + (size_t)DM*KK,   DM * KK);
  cast_f32_bf16<<<4096, 256, 0, stream>>>(Wv, wqkv + (size_t)2*DM*KK, DM * KK);
  rope_fct<<<1024, 256, 0, stream>>>(fct);

  gemm_qkv_rope<<<dim3(MM / 128, NQKV / 128), 256, 0, stream>>>(xb, wqkv, qb, kb, vtb, fct);

  cast_f32_bf16<<<4096, 256, 0, stream>>>(Wd, wdb, DM * KK);   // overwrites fct (dead)

  flash_attn<<<dim3(8, NH, BB), 256, 0, stream>>>(qb, kb, vtb, aob);
  gemm_out<<<dim3(MM / 128, DM / 128), 256, 0, stream>>>(aob, wdb, (float*)d_out);
}